// Round 14
// baseline (229.580 us; speedup 1.0000x reference)
//
#include <hip/hip_runtime.h>

#define BATCH 512
#define NPART 60
#define PFEAT 20
#define SFEAT 14
#define NVTX  5
#define HID   60
#define DE    20
#define DO    24
#define NCLS  2
#define HP    64          // cin row stride (halves)
#define SR    68          // LDS row stride in halves: 34 words -> 2-way banks max

typedef _Float16 half8  __attribute__((ext_vector_type(8)));
typedef _Float16 half4v __attribute__((ext_vector_type(4)));
typedef __fp16   fp16x2 __attribute__((ext_vector_type(2)));
typedef float    f32x4  __attribute__((ext_vector_type(4)));

__device__ __forceinline__ half4v pkcvt4(f32x4 a) {
    fp16x2 lo = __builtin_amdgcn_cvt_pkrtz(a[0], a[1]);
    fp16x2 hi = __builtin_amdgcn_cvt_pkrtz(a[2], a[3]);
    half4v r;
    r[0] = (_Float16)lo[0]; r[1] = (_Float16)lo[1];
    r[2] = (_Float16)hi[0]; r[3] = (_Float16)hi[1];
    return r;
}
__device__ __forceinline__ half4v relu4(half4v a) {
#pragma unroll
    for (int j = 0; j < 4; ++j)
        a[j] = (a[j] > (_Float16)0.f) ? a[j] : (_Float16)0.f;
    return a;
}
__device__ __forceinline__ f32x4 bias4(const float* b, int col4, int lim) {
    f32x4 z = {0.f, 0.f, 0.f, 0.f};
    return (col4 < lim) ? *(const f32x4*)(b + col4) : z;
}

// ---------------------------------------------------------------------------
// Pack kernel — 16 blocks, one element/thread (round-11, proven).
// ---------------------------------------------------------------------------
__global__ __launch_bounds__(256) void pack_kernel(
    const float* __restrict__ fr_w2, const float* __restrict__ fr_w3,
    const float* __restrict__ pv_w2, const float* __restrict__ pv_w3,
    const float* __restrict__ fo_w1, const float* __restrict__ fo_w2,
    const float* __restrict__ fo_w3,
    _Float16* __restrict__ frW2p, _Float16* __restrict__ frW3p16,
    _Float16* __restrict__ pvW2p, _Float16* __restrict__ pvW3p16,
    _Float16* __restrict__ foW1p, _Float16* __restrict__ foW2p16,
    _Float16* __restrict__ foW3p16)
{
    int idx = blockIdx.x*256 + threadIdx.x;    // 0..4095
    {   // x32 tables, u<4, kk<2
        int j  = idx & 7;
        int L  = (idx >> 3) & 63;
        int kk = (idx >> 9) & 1;
        int u  = idx >> 10;
        int k  = kk*32 + (L >> 4)*8 + j;
        int n  = u*16 + (L & 15);
        bool ok = (k < HID && n < HID);
        frW2p[idx] = (_Float16)(ok ? fr_w2[k*HID + n] : 0.f);
        pvW2p[idx] = (_Float16)(ok ? pv_w2[k*HID + n] : 0.f);
        foW1p[idx] = (_Float16)(ok ? fo_w1[k*HID + n] : 0.f);
    }
    {   // x16 table, u<4: fo_w2
        int j  = idx & 3;
        int L  = (idx >> 2) & 63;
        int kt = (idx >> 8) & 3;
        int u  = idx >> 10;
        int k  = kt*16 + (L >> 4)*4 + j;
        int n  = u*16 + (L & 15);
        foW2p16[idx] = (_Float16)((k < HID && n < HID) ? fo_w2[k*HID + n] : 0.f);
    }
    if (idx < 2048) {   // x16 tables, u<2: w3
        int j  = idx & 3;
        int L  = (idx >> 2) & 63;
        int kt = (idx >> 8) & 3;
        int u  = idx >> 10;
        int k  = kt*16 + (L >> 4)*4 + j;
        int n  = u*16 + (L & 15);
        frW3p16[idx] = (_Float16)((k < HID && n < DE) ? fr_w3[k*DE + n] : 0.f);
        pvW3p16[idx] = (_Float16)((k < HID && n < DE) ? pv_w3[k*DE + n] : 0.f);
        foW3p16[idx] = (_Float16)((k < HID && n < DO) ? fo_w3[k*DO + n] : 0.f);
    }
}

// ---------------------------------------------------------------------------
// Edge kernel (round-12 structure; round-14 change = register diet).
// grid 2*BATCH, block (bb, half): stage A in-LDS; fr groups r = half + 2k;
// half==0 blocks also do pv edges + reduction.
// Register diet: weights/biases are NOT held across the group loop — they are
// reloaded per group (L1-resident tables, coalesced, rematerializable), and
// __launch_bounds__(256, 5) caps the allocator at ~102 VGPR -> 5 waves/SIMD
// (vs r12's 128 VGPR -> 4 waves/SIMD; both pipes <35% = latency-bound).
// ---------------------------------------------------------------------------
__global__ __launch_bounds__(256, 5) void edge_fused_kernel(
    const float* __restrict__ x, const float* __restrict__ y,
    const float* __restrict__ fr_w1, const float* __restrict__ fr_b1,
    const float* __restrict__ pv_w1, const float* __restrict__ pv_b1,
    const float* __restrict__ fr_b2, const float* __restrict__ fr_b3,
    const float* __restrict__ pv_b2, const float* __restrict__ pv_b3,
    const half8*  __restrict__ frw2p, const half4v* __restrict__ frw3p16,
    const half8*  __restrict__ pvw2p, const half4v* __restrict__ pvw3p16,
    float* __restrict__ Epp, _Float16* __restrict__ EpvS)
{
    __shared__ __align__(16) _Float16 sFrA[NPART*SR];
    __shared__ __align__(16) _Float16 sFrB[NPART*SR];
    __shared__ __align__(16) _Float16 sPvA[NPART*SR];
    __shared__ __align__(16) _Float16 sPvV[NVTX*64];
    __shared__ __align__(16) _Float16 sEpvP[4][NPART*DE];

    int bb   = blockIdx.x >> 1;
    int half = blockIdx.x & 1;
    int wv   = threadIdx.x >> 6;
    int lane = threadIdx.x & 63;
    int ml   = lane & 15;
    int q    = lane >> 4;

    // ================= P0: stage A (wave wv owns row tile wv) ===============
    {
        int row = 16*wv + ml;
        int rr  = (row < NPART) ? row : 0;
        const float* xb = x + (size_t)bb*PFEAT*NPART;
        half8 bX;
#pragma unroll
        for (int j = 0; j < 8; ++j) {
            int k = q*8 + j;
            bX[j] = (_Float16)((k < PFEAT) ? xb[(size_t)k*NPART + rr] : 0.f);
        }
#pragma unroll
        for (int mat = 0; mat < 3; ++mat) {
            const float* W = (mat == 0) ? fr_w1 : (mat == 1) ? (fr_w1 + PFEAT*HID) : pv_w1;
            _Float16*   Ot = (mat == 0) ? sFrA : (mat == 1) ? sFrB : sPvA;
            f32x4 acc[4];
#pragma unroll
            for (int u = 0; u < 4; ++u) {
                int n = u*16 + ml;
                half8 w8;
#pragma unroll
                for (int j = 0; j < 8; ++j) {
                    int k = q*8 + j;
                    w8[j] = (_Float16)((k < PFEAT && n < HID) ? W[k*HID + n] : 0.f);
                }
                acc[u] = (mat == 0) ? bias4(fr_b1, u*16 + 4*q, HID - 3)
                                    : (f32x4){0.f, 0.f, 0.f, 0.f};
                acc[u] = __builtin_amdgcn_mfma_f32_16x16x32_f16(w8, bX, acc[u], 0, 0, 0);
            }
            if (row < NPART) {
#pragma unroll
                for (int u = 0; u < 4; ++u)
                    *(half4v*)(Ot + row*SR + u*16 + 4*q) = pkcvt4(acc[u]);
            }
        }
        // pvV
        for (int idx = threadIdx.x; idx < NVTX*64; idx += 256) {
            int v = idx >> 6;
            int h = idx & 63;
            float a = 0.f;
            if (h < HID) {
                a = pv_b1[h];
#pragma unroll
                for (int f = 0; f < SFEAT; ++f)
                    a += y[((size_t)bb*SFEAT + f)*NVTX + v] * pv_w1[(PFEAT + f)*HID + h];
            }
            sPvV[idx] = (_Float16)a;
        }
    }
    __syncthreads();

    // ================= P1a: fr-edge groups, r = half + 2k ===================
    for (int k = wv; k < NPART/2; k += 4) {
        int r = half + 2*k;
        half8 bA[4][2];
#pragma unroll
        for (int t = 0; t < 4; ++t) {
            int edge = 16*t + ml;
            int s = (edge < NPART-1) ? (edge + (edge >= r)) : 0;
#pragma unroll
            for (int kk = 0; kk < 2; ++kk) {
                half8 u8 = *(const half8*)(sFrA + r*SR + kk*32 + q*8);
                half8 v8 = *(const half8*)(sFrB + s*SR + kk*32 + q*8);
                half8 s8 = u8 + v8;
#pragma unroll
                for (int j = 0; j < 8; ++j) {
                    _Float16 vj = s8[j];
                    s8[j] = (vj > (_Float16)0.f) ? vj : (_Float16)0.f;
                }
                bA[t][kk] = s8;
            }
        }
        f32x4 acc2[4][4];
#pragma unroll
        for (int u = 0; u < 4; ++u) {
            f32x4 bi = bias4(fr_b2, u*16 + 4*q, HID - 3);
#pragma unroll
            for (int t = 0; t < 4; ++t) acc2[u][t] = bi;
        }
#pragma unroll
        for (int u = 0; u < 4; ++u) {
            half8 w0 = frw2p[(u*2 + 0)*64 + lane];   // reloaded per group (L1)
            half8 w1 = frw2p[(u*2 + 1)*64 + lane];
#pragma unroll
            for (int t = 0; t < 4; ++t) {
                acc2[u][t] = __builtin_amdgcn_mfma_f32_16x16x32_f16(w0, bA[t][0], acc2[u][t], 0, 0, 0);
                acc2[u][t] = __builtin_amdgcn_mfma_f32_16x16x32_f16(w1, bA[t][1], acc2[u][t], 0, 0, 0);
            }
        }
        half4v a3[4][4];
#pragma unroll
        for (int u = 0; u < 4; ++u)
#pragma unroll
            for (int t = 0; t < 4; ++t)
                a3[u][t] = relu4(pkcvt4(acc2[u][t]));
        f32x4 acc3[2][4];
#pragma unroll
        for (int v = 0; v < 2; ++v) {
            f32x4 bi = bias4(fr_b3, v*16 + 4*q, DE - 3);
#pragma unroll
            for (int t = 0; t < 4; ++t) acc3[v][t] = bi;
        }
#pragma unroll
        for (int v = 0; v < 2; ++v)
#pragma unroll
            for (int u = 0; u < 4; ++u) {
                half4v w = frw3p16[(v*4 + u)*64 + lane];   // reloaded per group (L1)
#pragma unroll
                for (int t = 0; t < 4; ++t)
                    acc3[v][t] = __builtin_amdgcn_mfma_f32_16x16x16f16(w, a3[u][t], acc3[v][t], 0, 0, 0);
            }
        // sum over edges -> Epp[bb][r]
#pragma unroll
        for (int v = 0; v < 2; ++v) {
            float s[4] = {0.f, 0.f, 0.f, 0.f};
#pragma unroll
            for (int t = 0; t < 4; ++t) {
                int edge = 16*t + ml;
                bool ok = edge < NPART-1;
#pragma unroll
                for (int i = 0; i < 4; ++i)
                    s[i] += ok ? fmaxf(acc3[v][t][i], 0.f) : 0.f;
            }
#pragma unroll
            for (int i = 0; i < 4; ++i) {
                s[i] += __shfl_xor(s[i], 1);
                s[i] += __shfl_xor(s[i], 2);
                s[i] += __shfl_xor(s[i], 4);
                s[i] += __shfl_xor(s[i], 8);
            }
            int col4 = v*16 + 4*q;
            if (ml == 0 && col4 < DE) {
                f32x4 o = {s[0], s[1], s[2], s[3]};
                *(f32x4*)(Epp + ((size_t)bb*NPART + r)*DE + col4) = o;
            }
        }
    }

    // ================= P1b: pv edges + reduction (half==0 blocks) ===========
    if (half == 0) {
        f32x4 sumPv[2][4];
#pragma unroll
        for (int v = 0; v < 2; ++v)
#pragma unroll
            for (int t = 0; t < 4; ++t) sumPv[v][t] = (f32x4){0.f, 0.f, 0.f, 0.f};

        for (int gv = wv; gv < NVTX; gv += 4) {
            half8 bA[4][2];
#pragma unroll
            for (int t = 0; t < 4; ++t) {
                int p = 16*t + ml;
                int s = (p < NPART) ? p : 0;
#pragma unroll
                for (int kk = 0; kk < 2; ++kk) {
                    half8 u8 = *(const half8*)(sPvV + gv*64 + kk*32 + q*8);
                    half8 v8 = *(const half8*)(sPvA + s*SR + kk*32 + q*8);
                    half8 s8 = u8 + v8;
#pragma unroll
                    for (int j = 0; j < 8; ++j) {
                        _Float16 vj = s8[j];
                        s8[j] = (vj > (_Float16)0.f) ? vj : (_Float16)0.f;
                    }
                    bA[t][kk] = s8;
                }
            }
            f32x4 acc2[4][4];
#pragma unroll
            for (int u = 0; u < 4; ++u) {
                f32x4 bi = bias4(pv_b2, u*16 + 4*q, HID - 3);
#pragma unroll
                for (int t = 0; t < 4; ++t) acc2[u][t] = bi;
            }
#pragma unroll
            for (int u = 0; u < 4; ++u) {
                half8 w0 = pvw2p[(u*2 + 0)*64 + lane];
                half8 w1 = pvw2p[(u*2 + 1)*64 + lane];
#pragma unroll
                for (int t = 0; t < 4; ++t) {
                    acc2[u][t] = __builtin_amdgcn_mfma_f32_16x16x32_f16(w0, bA[t][0], acc2[u][t], 0, 0, 0);
                    acc2[u][t] = __builtin_amdgcn_mfma_f32_16x16x32_f16(w1, bA[t][1], acc2[u][t], 0, 0, 0);
                }
            }
            half4v a3[4][4];
#pragma unroll
            for (int u = 0; u < 4; ++u)
#pragma unroll
                for (int t = 0; t < 4; ++t)
                    a3[u][t] = relu4(pkcvt4(acc2[u][t]));
            f32x4 acc3[2][4];
#pragma unroll
            for (int v = 0; v < 2; ++v) {
                f32x4 bi = bias4(pv_b3, v*16 + 4*q, DE - 3);
#pragma unroll
                for (int t = 0; t < 4; ++t) acc3[v][t] = bi;
            }
#pragma unroll
            for (int v = 0; v < 2; ++v)
#pragma unroll
                for (int u = 0; u < 4; ++u) {
                    half4v w = pvw3p16[(v*4 + u)*64 + lane];
#pragma unroll
                    for (int t = 0; t < 4; ++t)
                        acc3[v][t] = __builtin_amdgcn_mfma_f32_16x16x16f16(w, a3[u][t], acc3[v][t], 0, 0, 0);
                }
#pragma unroll
            for (int v = 0; v < 2; ++v)
#pragma unroll
                for (int t = 0; t < 4; ++t)
#pragma unroll
                    for (int i = 0; i < 4; ++i)
                        sumPv[v][t][i] += fmaxf(acc3[v][t][i], 0.f);
        }
#pragma unroll
        for (int v = 0; v < 2; ++v) {
            int col4 = v*16 + 4*q;
#pragma unroll
            for (int t = 0; t < 4; ++t) {
                int p = 16*t + ml;
                if (p < NPART && col4 < DE)
                    *(half4v*)(sEpvP[wv] + p*DE + col4) = pkcvt4(sumPv[v][t]);
            }
        }
        __syncthreads();   // block-uniform branch
        for (int idx = threadIdx.x; idx < NPART*DE; idx += 256) {
            float s = (float)sEpvP[0][idx] + (float)sEpvP[1][idx]
                    + (float)sEpvP[2][idx] + (float)sEpvP[3][idx];
            EpvS[(size_t)bb*NPART*DE + idx] = (_Float16)s;
        }
    }
}

// ---------------------------------------------------------------------------
// Prep: cin[b*NPART+p][64] = fp16 [ x(20) | Epp(20) | EpvS(20) | 0 ]
// ---------------------------------------------------------------------------
__global__ __launch_bounds__(256) void prep_kernel(
    const float* __restrict__ x, const float* __restrict__ Epp,
    const _Float16* __restrict__ EpvS, _Float16* __restrict__ cin)
{
    int idx = blockIdx.x*256 + threadIdx.x;   // BATCH*NPART*64 total
    int bp = idx >> 6;
    int k  = idx & 63;
    int b  = bp / NPART;
    int p  = bp - b*NPART;

    float v;
    if (k < PFEAT) {
        v = x[(b*PFEAT + k)*NPART + p];
    } else if (k < PFEAT + DE) {
        v = Epp[(size_t)bp*DE + (k - PFEAT)];
    } else if (k < PFEAT + 2*DE) {
        v = (float)EpvS[(size_t)bp*DE + (k - PFEAT - DE)];
    } else {
        v = 0.f;
    }
    cin[(size_t)bp*HP + k] = (_Float16)v;
}

// ---------------------------------------------------------------------------
// Stage D (round-9 proven): object MLP (transposed MFMA, zero LDS) + particle
// sum + fc head. 4 waves/block, one batch item per wave.
// ---------------------------------------------------------------------------
__global__ __launch_bounds__(256) void stageD_kernel(
    const _Float16* __restrict__ cin,
    const half8*  __restrict__ w1p, const half4v* __restrict__ w2p16,
    const half4v* __restrict__ w3p16,
    const float* __restrict__ b1, const float* __restrict__ b2,
    const float* __restrict__ b3,
    const float* __restrict__ fcw, const float* __restrict__ fcb,
    float* __restrict__ out)
{
    int wave = threadIdx.x >> 6;
    int lane = threadIdx.x & 63;
    int ml   = lane & 15;
    int q    = lane >> 4;
    int b    = blockIdx.x*4 + wave;

    const _Float16* base = cin + (size_t)b * NPART * HP;

    half8 bC[4][2];
#pragma unroll
    for (int t = 0; t < 4; ++t) {
        int p = 16*t + ml;
        int sp = (p < NPART) ? p : 0;
#pragma unroll
        for (int kk = 0; kk < 2; ++kk)
            bC[t][kk] = *(const half8*)(base + (size_t)sp*HP + kk*32 + q*8);
    }

    f32x4 acc1[4][4];
#pragma unroll
    for (int u = 0; u < 4; ++u) {
        f32x4 bi = bias4(b1, u*16 + 4*q, HID - 3);
#pragma unroll
        for (int t = 0; t < 4; ++t) acc1[u][t] = bi;
    }
#pragma unroll
    for (int u = 0; u < 4; ++u) {
        half8 w0 = w1p[(u*2 + 0)*64 + lane];
        half8 w1 = w1p[(u*2 + 1)*64 + lane];
#pragma unroll
        for (int t = 0; t < 4; ++t) {
            acc1[u][t] = __builtin_amdgcn_mfma_f32_16x16x32_f16(w0, bC[t][0], acc1[u][t], 0, 0, 0);
            acc1[u][t] = __builtin_amdgcn_mfma_f32_16x16x32_f16(w1, bC[t][1], acc1[u][t], 0, 0, 0);
        }
    }
    half4v a2[4][4];
#pragma unroll
    for (int u = 0; u < 4; ++u)
#pragma unroll
        for (int t = 0; t < 4; ++t)
            a2[u][t] = relu4(pkcvt4(acc1[u][t]));

    f32x4 acc2[4][4];
#pragma unroll
    for (int u = 0; u < 4; ++u) {
        f32x4 bi = bias4(b2, u*16 + 4*q, HID - 3);
#pragma unroll
        for (int t = 0; t < 4; ++t) acc2[u][t] = bi;
    }
#pragma unroll
    for (int u = 0; u < 4; ++u)
#pragma unroll
        for (int kt = 0; kt < 4; ++kt) {
            half4v w = w2p16[(u*4 + kt)*64 + lane];
#pragma unroll
            for (int t = 0; t < 4; ++t)
                acc2[u][t] = __builtin_amdgcn_mfma_f32_16x16x16f16(w, a2[kt][t], acc2[u][t], 0, 0, 0);
        }
    half4v a3[4][4];
#pragma unroll
    for (int u = 0; u < 4; ++u)
#pragma unroll
        for (int t = 0; t < 4; ++t)
            a3[u][t] = relu4(pkcvt4(acc2[u][t]));

    f32x4 acc3[2][4];
#pragma unroll
    for (int v = 0; v < 2; ++v) {
        f32x4 bi = bias4(b3, v*16 + 4*q, DO - 3);
#pragma unroll
        for (int t = 0; t < 4; ++t) acc3[v][t] = bi;
    }
#pragma unroll
    for (int v = 0; v < 2; ++v)
#pragma unroll
        for (int u = 0; u < 4; ++u) {
            half4v w = w3p16[(v*4 + u)*64 + lane];
#pragma unroll
            for (int t = 0; t < 4; ++t)
                acc3[v][t] = __builtin_amdgcn_mfma_f32_16x16x16f16(w, a3[u][t], acc3[v][t], 0, 0, 0);
        }

    float s[2][4];
#pragma unroll
    for (int v = 0; v < 2; ++v) {
#pragma unroll
        for (int i = 0; i < 4; ++i) s[v][i] = 0.f;
#pragma unroll
        for (int t = 0; t < 4; ++t) {
            int p = 16*t + ml;
            bool ok = p < NPART;
#pragma unroll
            for (int i = 0; i < 4; ++i) {
                float val = fmaxf(acc3[v][t][i], 0.f);
                s[v][i] += ok ? val : 0.f;
            }
        }
#pragma unroll
        for (int i = 0; i < 4; ++i) {
            s[v][i] += __shfl_xor(s[v][i], 1);
            s[v][i] += __shfl_xor(s[v][i], 2);
            s[v][i] += __shfl_xor(s[v][i], 4);
            s[v][i] += __shfl_xor(s[v][i], 8);
        }
    }
    float pc[NCLS];
#pragma unroll
    for (int c = 0; c < NCLS; ++c) {
        float acc = 0.f;
        if (ml == 0) {
#pragma unroll
            for (int v = 0; v < 2; ++v)
#pragma unroll
                for (int i = 0; i < 4; ++i) {
                    int col = v*16 + 4*q + i;
                    if (col < DO) acc += s[v][i] * fcw[col*NCLS + c];
                }
        }
        acc += __shfl_xor(acc, 16);
        acc += __shfl_xor(acc, 32);
        pc[c] = acc;
    }
    if (lane == 0) {
        out[b*NCLS + 0] = pc[0] + fcb[0];
        out[b*NCLS + 1] = pc[1] + fcb[1];
    }
}

// ---------------------------------------------------------------------------
extern "C" void kernel_launch(void* const* d_in, const int* in_sizes, int n_in,
                              void* d_out, int out_size, void* d_ws, size_t ws_size,
                              hipStream_t stream)
{
    const float* x     = (const float*)d_in[0];
    const float* y     = (const float*)d_in[1];
    const float* fr_w1 = (const float*)d_in[2];
    const float* fr_b1 = (const float*)d_in[3];
    const float* fr_w2 = (const float*)d_in[4];
    const float* fr_b2 = (const float*)d_in[5];
    const float* fr_w3 = (const float*)d_in[6];
    const float* fr_b3 = (const float*)d_in[7];
    const float* pv_w1 = (const float*)d_in[8];
    const float* pv_b1 = (const float*)d_in[9];
    const float* pv_w2 = (const float*)d_in[10];
    const float* pv_b2 = (const float*)d_in[11];
    const float* pv_w3 = (const float*)d_in[12];
    const float* pv_b3 = (const float*)d_in[13];
    const float* fo_w1 = (const float*)d_in[14];
    const float* fo_b1 = (const float*)d_in[15];
    const float* fo_w2 = (const float*)d_in[16];
    const float* fo_b2 = (const float*)d_in[17];
    const float* fo_w3 = (const float*)d_in[18];
    const float* fo_b3 = (const float*)d_in[19];
    const float* fc_w  = (const float*)d_in[20];
    const float* fc_b  = (const float*)d_in[21];
    float* out = (float*)d_out;

    char* wsb = (char*)d_ws;
    size_t off = 0;
    auto alloc = [&](size_t bytes) { char* p = wsb + off; off += (bytes + 255) & ~(size_t)255; return p; };

    float*    Epp  = (float*)   alloc((size_t)BATCH*NPART*DE*4);   // 2.46 MB
    _Float16* EpvS = (_Float16*)alloc((size_t)BATCH*NPART*DE*2);   // 1.23 MB
    _Float16* cin  = (_Float16*)alloc((size_t)BATCH*NPART*HP*2);   // 3.93 MB
    _Float16* frW2p   = (_Float16*)alloc(4096*2);
    _Float16* frW3p16 = (_Float16*)alloc(2048*2);
    _Float16* pvW2p   = (_Float16*)alloc(4096*2);
    _Float16* pvW3p16 = (_Float16*)alloc(2048*2);
    _Float16* foW1p   = (_Float16*)alloc(4096*2);
    _Float16* foW2p16 = (_Float16*)alloc(4096*2);
    _Float16* foW3p16 = (_Float16*)alloc(2048*2);

    pack_kernel<<<16, 256, 0, stream>>>(
        fr_w2, fr_w3, pv_w2, pv_w3, fo_w1, fo_w2, fo_w3,
        frW2p, frW3p16, pvW2p, pvW3p16, foW1p, foW2p16, foW3p16);

    edge_fused_kernel<<<2*BATCH, 256, 0, stream>>>(
        x, y, fr_w1, fr_b1, pv_w1, pv_b1,
        fr_b2, fr_b3, pv_b2, pv_b3,
        (const half8*)frW2p, (const half4v*)frW3p16,
        (const half8*)pvW2p, (const half4v*)pvW3p16,
        Epp, EpvS);

    prep_kernel<<<(BATCH*NPART*HP)/256, 256, 0, stream>>>(x, Epp, EpvS, cin);

    stageD_kernel<<<BATCH/4, 256, 0, stream>>>(cin,
        (const half8*)foW1p, (const half4v*)foW2p16, (const half4v*)foW3p16,
        fo_b1, fo_b2, fo_b3, fc_w, fc_b, out);
}

// Round 15
// 187.277 us; speedup vs baseline: 1.2259x; 1.2259x over previous
//
#include <hip/hip_runtime.h>

#define BATCH 512
#define NPART 60
#define PFEAT 20
#define SFEAT 14
#define NVTX  5
#define HID   60
#define DE    20
#define DO    24
#define NCLS  2
#define SR    68          // LDS row stride in halves: 34 words -> 2-way banks max

typedef _Float16 half8  __attribute__((ext_vector_type(8)));
typedef _Float16 half4v __attribute__((ext_vector_type(4)));
typedef __fp16   fp16x2 __attribute__((ext_vector_type(2)));
typedef float    f32x4  __attribute__((ext_vector_type(4)));

__device__ __forceinline__ half4v pkcvt4(f32x4 a) {
    fp16x2 lo = __builtin_amdgcn_cvt_pkrtz(a[0], a[1]);
    fp16x2 hi = __builtin_amdgcn_cvt_pkrtz(a[2], a[3]);
    half4v r;
    r[0] = (_Float16)lo[0]; r[1] = (_Float16)lo[1];
    r[2] = (_Float16)hi[0]; r[3] = (_Float16)hi[1];
    return r;
}
__device__ __forceinline__ half4v relu4(half4v a) {
#pragma unroll
    for (int j = 0; j < 4; ++j)
        a[j] = (a[j] > (_Float16)0.f) ? a[j] : (_Float16)0.f;
    return a;
}
__device__ __forceinline__ f32x4 bias4(const float* b, int col4, int lim) {
    f32x4 z = {0.f, 0.f, 0.f, 0.f};
    return (col4 < lim) ? *(const f32x4*)(b + col4) : z;
}

// ---------------------------------------------------------------------------
// Pack kernel — 16 blocks, one element/thread (round-11, proven).
// ---------------------------------------------------------------------------
__global__ __launch_bounds__(256) void pack_kernel(
    const float* __restrict__ fr_w2, const float* __restrict__ fr_w3,
    const float* __restrict__ pv_w2, const float* __restrict__ pv_w3,
    const float* __restrict__ fo_w1, const float* __restrict__ fo_w2,
    const float* __restrict__ fo_w3,
    _Float16* __restrict__ frW2p, _Float16* __restrict__ frW3p16,
    _Float16* __restrict__ pvW2p, _Float16* __restrict__ pvW3p16,
    _Float16* __restrict__ foW1p, _Float16* __restrict__ foW2p16,
    _Float16* __restrict__ foW3p16)
{
    int idx = blockIdx.x*256 + threadIdx.x;    // 0..4095
    {   // x32 tables, u<4, kk<2
        int j  = idx & 7;
        int L  = (idx >> 3) & 63;
        int kk = (idx >> 9) & 1;
        int u  = idx >> 10;
        int k  = kk*32 + (L >> 4)*8 + j;
        int n  = u*16 + (L & 15);
        bool ok = (k < HID && n < HID);
        frW2p[idx] = (_Float16)(ok ? fr_w2[k*HID + n] : 0.f);
        pvW2p[idx] = (_Float16)(ok ? pv_w2[k*HID + n] : 0.f);
        foW1p[idx] = (_Float16)(ok ? fo_w1[k*HID + n] : 0.f);
    }
    {   // x16 table, u<4: fo_w2
        int j  = idx & 3;
        int L  = (idx >> 2) & 63;
        int kt = (idx >> 8) & 3;
        int u  = idx >> 10;
        int k  = kt*16 + (L >> 4)*4 + j;
        int n  = u*16 + (L & 15);
        foW2p16[idx] = (_Float16)((k < HID && n < HID) ? fo_w2[k*HID + n] : 0.f);
    }
    if (idx < 2048) {   // x16 tables, u<2: w3
        int j  = idx & 3;
        int L  = (idx >> 2) & 63;
        int kt = (idx >> 8) & 3;
        int u  = idx >> 10;
        int k  = kt*16 + (L >> 4)*4 + j;
        int n  = u*16 + (L & 15);
        frW3p16[idx] = (_Float16)((k < HID && n < DE) ? fr_w3[k*DE + n] : 0.f);
        pvW3p16[idx] = (_Float16)((k < HID && n < DE) ? pv_w3[k*DE + n] : 0.f);
        foW3p16[idx] = (_Float16)((k < HID && n < DO) ? fo_w3[k*DO + n] : 0.f);
    }
}

// ---------------------------------------------------------------------------
// Fused network kernel v2: 512 threads (8 waves), one block per batch item.
// Register-interleaved layer 2->3 (no acc2[4][4] array -> target VGPR <= 128
// so 2 blocks/CU = 4 waves/SIMD; r11 was 148 VGPR / 2 waves/SIMD).
// Phases: P0 stage A (12 (mat,tile) tasks over 8 waves) + pvV; P1a fr groups
// r = wv+8k -> sEpp; P1b pv groups gv = wv (<5) -> sEpvP[5]; P2 cin gather
// (aliases sFrA); P3 object MLP on waves 0-3 -> sDsum; fc head wave 0.
// ---------------------------------------------------------------------------
__global__ __launch_bounds__(512, 4) void fused_kernel(
    const float* __restrict__ x, const float* __restrict__ y,
    const float* __restrict__ fr_w1, const float* __restrict__ fr_b1,
    const float* __restrict__ fr_b2, const float* __restrict__ fr_b3,
    const float* __restrict__ pv_w1, const float* __restrict__ pv_b1,
    const float* __restrict__ pv_b2, const float* __restrict__ pv_b3,
    const float* __restrict__ fo_b1, const float* __restrict__ fo_b2,
    const float* __restrict__ fo_b3,
    const float* __restrict__ fcw, const float* __restrict__ fcb,
    const half8*  __restrict__ frw2p, const half4v* __restrict__ frw3p16,
    const half8*  __restrict__ pvw2p, const half4v* __restrict__ pvw3p16,
    const half8*  __restrict__ fow1p, const half4v* __restrict__ fow2p16,
    const half4v* __restrict__ fow3p16,
    float* __restrict__ out)
{
    __shared__ __align__(16) _Float16 sFrA[NPART*SR];     // P2+: aliased as sCin
    __shared__ __align__(16) _Float16 sFrB[NPART*SR];
    __shared__ __align__(16) _Float16 sPvA[NPART*SR];
    __shared__ __align__(16) _Float16 sPvV[NVTX*64];
    __shared__ __align__(16) _Float16 sEpp[NPART*DE];
    __shared__ __align__(16) _Float16 sEpvP[NVTX*NPART*DE];
    __shared__ __align__(16) float    sDsum[4][DO];
    _Float16* sCin = sFrA;

    int bb   = blockIdx.x;
    int wv   = threadIdx.x >> 6;     // 0..7
    int lane = threadIdx.x & 63;
    int ml   = lane & 15;
    int q    = lane >> 4;

    // ================= P0: stage A ==========================================
    {
        int tile = wv & 3;
        int row  = 16*tile + ml;
        int rr   = (row < NPART) ? row : 0;
        const float* xb = x + (size_t)bb*PFEAT*NPART;
        half8 bX;
#pragma unroll
        for (int j = 0; j < 8; ++j) {
            int k = q*8 + j;
            bX[j] = (_Float16)((k < PFEAT) ? xb[(size_t)k*NPART + rr] : 0.f);
        }
#pragma unroll
        for (int task = 0; task < 2; ++task) {
            const float* W; const float* bset; _Float16* Ot;
            if (wv < 4) {
                if (task == 0) { W = fr_w1;  bset = fr_b1;  Ot = sFrA; }
                else           { W = pv_w1;  bset = nullptr; Ot = sPvA; }
            } else {
                if (task == 1) break;
                W = fr_w1 + PFEAT*HID; bset = nullptr; Ot = sFrB;
            }
#pragma unroll
            for (int u = 0; u < 4; ++u) {
                int n = u*16 + ml;
                half8 w8;
#pragma unroll
                for (int j = 0; j < 8; ++j) {
                    int k = q*8 + j;
                    w8[j] = (_Float16)((k < PFEAT && n < HID) ? W[k*HID + n] : 0.f);
                }
                f32x4 acc = bset ? bias4(bset, u*16 + 4*q, HID - 3)
                                 : (f32x4){0.f, 0.f, 0.f, 0.f};
                acc = __builtin_amdgcn_mfma_f32_16x16x32_f16(w8, bX, acc, 0, 0, 0);
                if (row < NPART)
                    *(half4v*)(Ot + row*SR + u*16 + 4*q) = pkcvt4(acc);
            }
        }
        // pvV: 320 outputs, one per thread
        for (int idx = threadIdx.x; idx < NVTX*64; idx += 512) {
            int v = idx >> 6;
            int h = idx & 63;
            float a = 0.f;
            if (h < HID) {
                a = pv_b1[h];
#pragma unroll
                for (int f = 0; f < SFEAT; ++f)
                    a += y[((size_t)bb*SFEAT + f)*NVTX + v] * pv_w1[(PFEAT + f)*HID + h];
            }
            sPvV[idx] = (_Float16)a;
        }
    }
    __syncthreads();

    // ================= P1a: fr-edge groups, r = wv + 8k =====================
    for (int r = wv; r < NPART; r += 8) {
        half8 bA[4][2];
#pragma unroll
        for (int t = 0; t < 4; ++t) {
            int edge = 16*t + ml;
            int s = (edge < NPART-1) ? (edge + (edge >= r)) : 0;
#pragma unroll
            for (int kk = 0; kk < 2; ++kk) {
                half8 u8 = *(const half8*)(sFrA + r*SR + kk*32 + q*8);
                half8 v8 = *(const half8*)(sFrB + s*SR + kk*32 + q*8);
                half8 s8 = u8 + v8;
#pragma unroll
                for (int j = 0; j < 8; ++j) {
                    _Float16 vj = s8[j];
                    s8[j] = (vj > (_Float16)0.f) ? vj : (_Float16)0.f;
                }
                bA[t][kk] = s8;
            }
        }
        // interleaved layers 2->3: per-u acc2 column, fed straight to acc3
        f32x4 acc3[2][4];
#pragma unroll
        for (int v = 0; v < 2; ++v) {
            f32x4 bi = bias4(fr_b3, v*16 + 4*q, DE - 3);
#pragma unroll
            for (int t = 0; t < 4; ++t) acc3[v][t] = bi;
        }
#pragma unroll
        for (int u = 0; u < 4; ++u) {
            half8 w0 = frw2p[(u*2 + 0)*64 + lane];
            half8 w1 = frw2p[(u*2 + 1)*64 + lane];
            f32x4 bi2 = bias4(fr_b2, u*16 + 4*q, HID - 3);
            half4v a3u[4];
#pragma unroll
            for (int t = 0; t < 4; ++t) {
                f32x4 a = bi2;
                a = __builtin_amdgcn_mfma_f32_16x16x32_f16(w0, bA[t][0], a, 0, 0, 0);
                a = __builtin_amdgcn_mfma_f32_16x16x32_f16(w1, bA[t][1], a, 0, 0, 0);
                a3u[t] = relu4(pkcvt4(a));
            }
            half4v w3a = frw3p16[(0*4 + u)*64 + lane];
            half4v w3b = frw3p16[(1*4 + u)*64 + lane];
#pragma unroll
            for (int t = 0; t < 4; ++t) {
                acc3[0][t] = __builtin_amdgcn_mfma_f32_16x16x16f16(w3a, a3u[t], acc3[0][t], 0, 0, 0);
                acc3[1][t] = __builtin_amdgcn_mfma_f32_16x16x16f16(w3b, a3u[t], acc3[1][t], 0, 0, 0);
            }
        }
        // sum over edges -> sEpp[r] (f16)
#pragma unroll
        for (int v = 0; v < 2; ++v) {
            float s[4] = {0.f, 0.f, 0.f, 0.f};
#pragma unroll
            for (int t = 0; t < 4; ++t) {
                int edge = 16*t + ml;
                bool ok = edge < NPART-1;
#pragma unroll
                for (int i = 0; i < 4; ++i)
                    s[i] += ok ? fmaxf(acc3[v][t][i], 0.f) : 0.f;
            }
#pragma unroll
            for (int i = 0; i < 4; ++i) {
                s[i] += __shfl_xor(s[i], 1);
                s[i] += __shfl_xor(s[i], 2);
                s[i] += __shfl_xor(s[i], 4);
                s[i] += __shfl_xor(s[i], 8);
            }
            int col4 = v*16 + 4*q;
            if (ml == 0 && col4 < DE) {
                f32x4 o = {s[0], s[1], s[2], s[3]};
                *(half4v*)(sEpp + r*DE + col4) = pkcvt4(o);
            }
        }
    }

    // ================= P1b: pv groups, gv = wv (waves 0-4) ==================
    if (wv < NVTX) {
        int gv = wv;
        half8 bA[4][2];
#pragma unroll
        for (int t = 0; t < 4; ++t) {
            int p = 16*t + ml;
            int s = (p < NPART) ? p : 0;
#pragma unroll
            for (int kk = 0; kk < 2; ++kk) {
                half8 u8 = *(const half8*)(sPvV + gv*64 + kk*32 + q*8);
                half8 v8 = *(const half8*)(sPvA + s*SR + kk*32 + q*8);
                half8 s8 = u8 + v8;
#pragma unroll
                for (int j = 0; j < 8; ++j) {
                    _Float16 vj = s8[j];
                    s8[j] = (vj > (_Float16)0.f) ? vj : (_Float16)0.f;
                }
                bA[t][kk] = s8;
            }
        }
        f32x4 acc3[2][4];
#pragma unroll
        for (int v = 0; v < 2; ++v) {
            f32x4 bi = bias4(pv_b3, v*16 + 4*q, DE - 3);
#pragma unroll
            for (int t = 0; t < 4; ++t) acc3[v][t] = bi;
        }
#pragma unroll
        for (int u = 0; u < 4; ++u) {
            half8 w0 = pvw2p[(u*2 + 0)*64 + lane];
            half8 w1 = pvw2p[(u*2 + 1)*64 + lane];
            f32x4 bi2 = bias4(pv_b2, u*16 + 4*q, HID - 3);
            half4v a3u[4];
#pragma unroll
            for (int t = 0; t < 4; ++t) {
                f32x4 a = bi2;
                a = __builtin_amdgcn_mfma_f32_16x16x32_f16(w0, bA[t][0], a, 0, 0, 0);
                a = __builtin_amdgcn_mfma_f32_16x16x32_f16(w1, bA[t][1], a, 0, 0, 0);
                a3u[t] = relu4(pkcvt4(a));
            }
            half4v w3a = pvw3p16[(0*4 + u)*64 + lane];
            half4v w3b = pvw3p16[(1*4 + u)*64 + lane];
#pragma unroll
            for (int t = 0; t < 4; ++t) {
                acc3[0][t] = __builtin_amdgcn_mfma_f32_16x16x16f16(w3a, a3u[t], acc3[0][t], 0, 0, 0);
                acc3[1][t] = __builtin_amdgcn_mfma_f32_16x16x16f16(w3b, a3u[t], acc3[1][t], 0, 0, 0);
            }
        }
#pragma unroll
        for (int v = 0; v < 2; ++v) {
            int col4 = v*16 + 4*q;
#pragma unroll
            for (int t = 0; t < 4; ++t) {
                int p = 16*t + ml;
                if (p < NPART && col4 < DE) {
                    half4v hv = relu4(pkcvt4(acc3[v][t]));
                    *(half4v*)(sEpvP + (gv*NPART + p)*DE + col4) = hv;
                }
            }
        }
    }
    __syncthreads();

    // ================= P2: cin gather into sCin (aliases sFrA) ==============
    for (int idx = threadIdx.x; idx < NPART*64; idx += 512) {
        int p = idx >> 6;
        int k = idx & 63;
        _Float16 v;
        if (k < PFEAT) {
            v = (_Float16)x[((size_t)bb*PFEAT + k)*NPART + p];
        } else if (k < PFEAT + DE) {
            v = sEpp[p*DE + (k - PFEAT)];
        } else if (k < PFEAT + 2*DE) {
            int c = k - PFEAT - DE;
            float s = 0.f;
#pragma unroll
            for (int g5 = 0; g5 < NVTX; ++g5)
                s += (float)sEpvP[(g5*NPART + p)*DE + c];
            v = (_Float16)s;
        } else {
            v = (_Float16)0.f;
        }
        sCin[p*SR + k] = v;
    }
    __syncthreads();

    // ================= P3: object MLP (waves 0-3, tile = wv) ================
    if (wv < 4) {
        int p = 16*wv + ml;
        int sp = (p < NPART) ? p : 0;
        half8 bC[2];
#pragma unroll
        for (int kk = 0; kk < 2; ++kk)
            bC[kk] = *(const half8*)(sCin + sp*SR + kk*32 + q*8);

        f32x4 acc1[4];
#pragma unroll
        for (int u = 0; u < 4; ++u) {
            acc1[u] = bias4(fo_b1, u*16 + 4*q, HID - 3);
            acc1[u] = __builtin_amdgcn_mfma_f32_16x16x32_f16(fow1p[(u*2 + 0)*64 + lane], bC[0], acc1[u], 0, 0, 0);
            acc1[u] = __builtin_amdgcn_mfma_f32_16x16x32_f16(fow1p[(u*2 + 1)*64 + lane], bC[1], acc1[u], 0, 0, 0);
        }
        half4v a2[4];
#pragma unroll
        for (int u = 0; u < 4; ++u) a2[u] = relu4(pkcvt4(acc1[u]));

        f32x4 acc2[4];
#pragma unroll
        for (int u = 0; u < 4; ++u) {
            acc2[u] = bias4(fo_b2, u*16 + 4*q, HID - 3);
#pragma unroll
            for (int kt = 0; kt < 4; ++kt)
                acc2[u] = __builtin_amdgcn_mfma_f32_16x16x16f16(fow2p16[(u*4 + kt)*64 + lane], a2[kt], acc2[u], 0, 0, 0);
        }
        half4v a3[4];
#pragma unroll
        for (int u = 0; u < 4; ++u) a3[u] = relu4(pkcvt4(acc2[u]));

        f32x4 acc3[2];
#pragma unroll
        for (int v = 0; v < 2; ++v) {
            acc3[v] = bias4(fo_b3, v*16 + 4*q, DO - 3);
#pragma unroll
            for (int u = 0; u < 4; ++u)
                acc3[v] = __builtin_amdgcn_mfma_f32_16x16x16f16(fow3p16[(v*4 + u)*64 + lane], a3[u], acc3[v], 0, 0, 0);
        }
#pragma unroll
        for (int v = 0; v < 2; ++v) {
            float s[4];
            bool ok = p < NPART;
#pragma unroll
            for (int i = 0; i < 4; ++i)
                s[i] = ok ? fmaxf(acc3[v][i], 0.f) : 0.f;
#pragma unroll
            for (int i = 0; i < 4; ++i) {
                s[i] += __shfl_xor(s[i], 1);
                s[i] += __shfl_xor(s[i], 2);
                s[i] += __shfl_xor(s[i], 4);
                s[i] += __shfl_xor(s[i], 8);
            }
            int col4 = v*16 + 4*q;
            if (ml == 0 && col4 < DO) {
                f32x4 o = {s[0], s[1], s[2], s[3]};
                *(f32x4*)(sDsum[wv] + col4) = o;
            }
        }
    }
    __syncthreads();

    // ================= fc head (wave 0) =====================================
    if (wv == 0) {
        float tot = 0.f;
        if (lane < DO) {
#pragma unroll
            for (int w4 = 0; w4 < 4; ++w4) tot += sDsum[w4][lane];
        }
        float p0 = (lane < DO) ? tot * fcw[lane*NCLS + 0] : 0.f;
        float p1 = (lane < DO) ? tot * fcw[lane*NCLS + 1] : 0.f;
#pragma unroll
        for (int d = 1; d <= 16; d <<= 1) {
            p0 += __shfl_xor(p0, d);
            p1 += __shfl_xor(p1, d);
        }
        if (lane == 0) {
            out[bb*NCLS + 0] = p0 + fcb[0];
            out[bb*NCLS + 1] = p1 + fcb[1];
        }
    }
}

// ---------------------------------------------------------------------------
extern "C" void kernel_launch(void* const* d_in, const int* in_sizes, int n_in,
                              void* d_out, int out_size, void* d_ws, size_t ws_size,
                              hipStream_t stream)
{
    const float* x     = (const float*)d_in[0];
    const float* y     = (const float*)d_in[1];
    const float* fr_w1 = (const float*)d_in[2];
    const float* fr_b1 = (const float*)d_in[3];
    const float* fr_w2 = (const float*)d_in[4];
    const float* fr_b2 = (const float*)d_in[5];
    const float* fr_w3 = (const float*)d_in[6];
    const float* fr_b3 = (const float*)d_in[7];
    const float* pv_w1 = (const float*)d_in[8];
    const float* pv_b1 = (const float*)d_in[9];
    const float* pv_w2 = (const float*)d_in[10];
    const float* pv_b2 = (const float*)d_in[11];
    const float* pv_w3 = (const float*)d_in[12];
    const float* pv_b3 = (const float*)d_in[13];
    const float* fo_w1 = (const float*)d_in[14];
    const float* fo_b1 = (const float*)d_in[15];
    const float* fo_w2 = (const float*)d_in[16];
    const float* fo_b2 = (const float*)d_in[17];
    const float* fo_w3 = (const float*)d_in[18];
    const float* fo_b3 = (const float*)d_in[19];
    const float* fc_w  = (const float*)d_in[20];
    const float* fc_b  = (const float*)d_in[21];
    float* out = (float*)d_out;

    char* wsb = (char*)d_ws;
    size_t off = 0;
    auto alloc = [&](size_t bytes) { char* p = wsb + off; off += (bytes + 255) & ~(size_t)255; return p; };

    _Float16* frW2p   = (_Float16*)alloc(4096*2);
    _Float16* frW3p16 = (_Float16*)alloc(2048*2);
    _Float16* pvW2p   = (_Float16*)alloc(4096*2);
    _Float16* pvW3p16 = (_Float16*)alloc(2048*2);
    _Float16* foW1p   = (_Float16*)alloc(4096*2);
    _Float16* foW2p16 = (_Float16*)alloc(4096*2);
    _Float16* foW3p16 = (_Float16*)alloc(2048*2);

    pack_kernel<<<16, 256, 0, stream>>>(
        fr_w2, fr_w3, pv_w2, pv_w3, fo_w1, fo_w2, fo_w3,
        frW2p, frW3p16, pvW2p, pvW3p16, foW1p, foW2p16, foW3p16);

    fused_kernel<<<BATCH, 512, 0, stream>>>(
        x, y, fr_w1, fr_b1, fr_b2, fr_b3,
        pv_w1, pv_b1, pv_b2, pv_b3,
        fo_b1, fo_b2, fo_b3, fc_w, fc_b,
        (const half8*)frW2p, (const half4v*)frW3p16,
        (const half8*)pvW2p, (const half4v*)pvW3p16,
        (const half8*)foW1p, (const half4v*)foW2p16, (const half4v*)foW3p16,
        out);
}

// Round 16
// 167.539 us; speedup vs baseline: 1.3703x; 1.1178x over previous
//
#include <hip/hip_runtime.h>

#define BATCH 512
#define NPART 60
#define PFEAT 20
#define SFEAT 14
#define NVTX  5
#define HID   60
#define DE    20
#define DO    24
#define NCLS  2
#define SR    68          // LDS row stride in halves: 34 words -> 2-way banks max

typedef _Float16 half8  __attribute__((ext_vector_type(8)));
typedef _Float16 half4v __attribute__((ext_vector_type(4)));
typedef __fp16   fp16x2 __attribute__((ext_vector_type(2)));
typedef float    f32x4  __attribute__((ext_vector_type(4)));

__device__ __forceinline__ half4v pkcvt4(f32x4 a) {
    fp16x2 lo = __builtin_amdgcn_cvt_pkrtz(a[0], a[1]);
    fp16x2 hi = __builtin_amdgcn_cvt_pkrtz(a[2], a[3]);
    half4v r;
    r[0] = (_Float16)lo[0]; r[1] = (_Float16)lo[1];
    r[2] = (_Float16)hi[0]; r[3] = (_Float16)hi[1];
    return r;
}
__device__ __forceinline__ half4v relu4(half4v a) {
#pragma unroll
    for (int j = 0; j < 4; ++j)
        a[j] = (a[j] > (_Float16)0.f) ? a[j] : (_Float16)0.f;
    return a;
}
__device__ __forceinline__ f32x4 bias4(const float* b, int col4, int lim) {
    f32x4 z = {0.f, 0.f, 0.f, 0.f};
    return (col4 < lim) ? *(const f32x4*)(b + col4) : z;
}

// ---------------------------------------------------------------------------
// Pack kernel — 16 blocks, one element/thread (round-11, proven).
// ---------------------------------------------------------------------------
__global__ __launch_bounds__(256) void pack_kernel(
    const float* __restrict__ fr_w2, const float* __restrict__ fr_w3,
    const float* __restrict__ pv_w2, const float* __restrict__ pv_w3,
    const float* __restrict__ fo_w1, const float* __restrict__ fo_w2,
    const float* __restrict__ fo_w3,
    _Float16* __restrict__ frW2p, _Float16* __restrict__ frW3p16,
    _Float16* __restrict__ pvW2p, _Float16* __restrict__ pvW3p16,
    _Float16* __restrict__ foW1p, _Float16* __restrict__ foW2p16,
    _Float16* __restrict__ foW3p16)
{
    int idx = blockIdx.x*256 + threadIdx.x;    // 0..4095
    {   // x32 tables, u<4, kk<2
        int j  = idx & 7;
        int L  = (idx >> 3) & 63;
        int kk = (idx >> 9) & 1;
        int u  = idx >> 10;
        int k  = kk*32 + (L >> 4)*8 + j;
        int n  = u*16 + (L & 15);
        bool ok = (k < HID && n < HID);
        frW2p[idx] = (_Float16)(ok ? fr_w2[k*HID + n] : 0.f);
        pvW2p[idx] = (_Float16)(ok ? pv_w2[k*HID + n] : 0.f);
        foW1p[idx] = (_Float16)(ok ? fo_w1[k*HID + n] : 0.f);
    }
    {   // x16 table, u<4: fo_w2
        int j  = idx & 3;
        int L  = (idx >> 2) & 63;
        int kt = (idx >> 8) & 3;
        int u  = idx >> 10;
        int k  = kt*16 + (L >> 4)*4 + j;
        int n  = u*16 + (L & 15);
        foW2p16[idx] = (_Float16)((k < HID && n < HID) ? fo_w2[k*HID + n] : 0.f);
    }
    if (idx < 2048) {   // x16 tables, u<2: w3
        int j  = idx & 3;
        int L  = (idx >> 2) & 63;
        int kt = (idx >> 8) & 3;
        int u  = idx >> 10;
        int k  = kt*16 + (L >> 4)*4 + j;
        int n  = u*16 + (L & 15);
        frW3p16[idx] = (_Float16)((k < HID && n < DE) ? fr_w3[k*DE + n] : 0.f);
        pvW3p16[idx] = (_Float16)((k < HID && n < DE) ? pv_w3[k*DE + n] : 0.f);
        foW3p16[idx] = (_Float16)((k < HID && n < DO) ? fo_w3[k*DO + n] : 0.f);
    }
}

// ---------------------------------------------------------------------------
// Fused network kernel v3: 512 threads (8 waves), one block per batch item.
// NO min-waves hint (r15's (512,4) made the allocator spill to 64 VGPR +
// 200 MB scratch traffic). Pressure is cut structurally instead: edge tiles
// processed in t-PAIRS so only bA[2][2] + acc3[2][2] are live at once
// (peak ~100 VGPR -> natural allocation <=128 -> 2 blocks/CU, no spill).
// ---------------------------------------------------------------------------
__global__ __launch_bounds__(512) void fused_kernel(
    const float* __restrict__ x, const float* __restrict__ y,
    const float* __restrict__ fr_w1, const float* __restrict__ fr_b1,
    const float* __restrict__ fr_b2, const float* __restrict__ fr_b3,
    const float* __restrict__ pv_w1, const float* __restrict__ pv_b1,
    const float* __restrict__ pv_b2, const float* __restrict__ pv_b3,
    const float* __restrict__ fo_b1, const float* __restrict__ fo_b2,
    const float* __restrict__ fo_b3,
    const float* __restrict__ fcw, const float* __restrict__ fcb,
    const half8*  __restrict__ frw2p, const half4v* __restrict__ frw3p16,
    const half8*  __restrict__ pvw2p, const half4v* __restrict__ pvw3p16,
    const half8*  __restrict__ fow1p, const half4v* __restrict__ fow2p16,
    const half4v* __restrict__ fow3p16,
    float* __restrict__ out)
{
    __shared__ __align__(16) _Float16 sFrA[NPART*SR];     // P2+: aliased as sCin
    __shared__ __align__(16) _Float16 sFrB[NPART*SR];
    __shared__ __align__(16) _Float16 sPvA[NPART*SR];
    __shared__ __align__(16) _Float16 sPvV[NVTX*64];
    __shared__ __align__(16) _Float16 sEpp[NPART*DE];
    __shared__ __align__(16) _Float16 sEpvP[NVTX*NPART*DE];
    __shared__ __align__(16) float    sDsum[4][DO];
    _Float16* sCin = sFrA;

    int bb   = blockIdx.x;
    int wv   = threadIdx.x >> 6;     // 0..7
    int lane = threadIdx.x & 63;
    int ml   = lane & 15;
    int q    = lane >> 4;

    // ================= P0: stage A ==========================================
    {
        int tile = wv & 3;
        int row  = 16*tile + ml;
        int rr   = (row < NPART) ? row : 0;
        const float* xb = x + (size_t)bb*PFEAT*NPART;
        half8 bX;
#pragma unroll
        for (int j = 0; j < 8; ++j) {
            int k = q*8 + j;
            bX[j] = (_Float16)((k < PFEAT) ? xb[(size_t)k*NPART + rr] : 0.f);
        }
#pragma unroll
        for (int task = 0; task < 2; ++task) {
            const float* W; const float* bset; _Float16* Ot;
            if (wv < 4) {
                if (task == 0) { W = fr_w1;  bset = fr_b1;  Ot = sFrA; }
                else           { W = pv_w1;  bset = nullptr; Ot = sPvA; }
            } else {
                if (task == 1) break;
                W = fr_w1 + PFEAT*HID; bset = nullptr; Ot = sFrB;
            }
#pragma unroll
            for (int u = 0; u < 4; ++u) {
                int n = u*16 + ml;
                half8 w8;
#pragma unroll
                for (int j = 0; j < 8; ++j) {
                    int k = q*8 + j;
                    w8[j] = (_Float16)((k < PFEAT && n < HID) ? W[k*HID + n] : 0.f);
                }
                f32x4 acc = bset ? bias4(bset, u*16 + 4*q, HID - 3)
                                 : (f32x4){0.f, 0.f, 0.f, 0.f};
                acc = __builtin_amdgcn_mfma_f32_16x16x32_f16(w8, bX, acc, 0, 0, 0);
                if (row < NPART)
                    *(half4v*)(Ot + row*SR + u*16 + 4*q) = pkcvt4(acc);
            }
        }
        // pvV: 320 outputs, one per thread
        for (int idx = threadIdx.x; idx < NVTX*64; idx += 512) {
            int v = idx >> 6;
            int h = idx & 63;
            float a = 0.f;
            if (h < HID) {
                a = pv_b1[h];
#pragma unroll
                for (int f = 0; f < SFEAT; ++f)
                    a += y[((size_t)bb*SFEAT + f)*NVTX + v] * pv_w1[(PFEAT + f)*HID + h];
            }
            sPvV[idx] = (_Float16)a;
        }
    }
    __syncthreads();

    // ================= P1a: fr-edge groups, r = wv + 8k, t-pair halves ======
    for (int r = wv; r < NPART; r += 8) {
        float s[2][4];
#pragma unroll
        for (int v = 0; v < 2; ++v)
#pragma unroll
            for (int i = 0; i < 4; ++i) s[v][i] = 0.f;

#pragma unroll
        for (int th = 0; th < 2; ++th) {
            half8 bA[2][2];
#pragma unroll
            for (int tl = 0; tl < 2; ++tl) {
                int edge = 16*(2*th + tl) + ml;
                int sr = (edge < NPART-1) ? (edge + (edge >= r)) : 0;
#pragma unroll
                for (int kk = 0; kk < 2; ++kk) {
                    half8 u8 = *(const half8*)(sFrA + r*SR + kk*32 + q*8);
                    half8 v8 = *(const half8*)(sFrB + sr*SR + kk*32 + q*8);
                    half8 s8 = u8 + v8;
#pragma unroll
                    for (int j = 0; j < 8; ++j) {
                        _Float16 vj = s8[j];
                        s8[j] = (vj > (_Float16)0.f) ? vj : (_Float16)0.f;
                    }
                    bA[tl][kk] = s8;
                }
            }
            f32x4 acc3[2][2];
#pragma unroll
            for (int v = 0; v < 2; ++v) {
                f32x4 bi = bias4(fr_b3, v*16 + 4*q, DE - 3);
#pragma unroll
                for (int tl = 0; tl < 2; ++tl) acc3[v][tl] = bi;
            }
#pragma unroll
            for (int u = 0; u < 4; ++u) {
                half8 w0 = frw2p[(u*2 + 0)*64 + lane];
                half8 w1 = frw2p[(u*2 + 1)*64 + lane];
                f32x4 bi2 = bias4(fr_b2, u*16 + 4*q, HID - 3);
                half4v a3u[2];
#pragma unroll
                for (int tl = 0; tl < 2; ++tl) {
                    f32x4 a = bi2;
                    a = __builtin_amdgcn_mfma_f32_16x16x32_f16(w0, bA[tl][0], a, 0, 0, 0);
                    a = __builtin_amdgcn_mfma_f32_16x16x32_f16(w1, bA[tl][1], a, 0, 0, 0);
                    a3u[tl] = relu4(pkcvt4(a));
                }
                half4v w3a = frw3p16[(0*4 + u)*64 + lane];
                half4v w3b = frw3p16[(1*4 + u)*64 + lane];
#pragma unroll
                for (int tl = 0; tl < 2; ++tl) {
                    acc3[0][tl] = __builtin_amdgcn_mfma_f32_16x16x16f16(w3a, a3u[tl], acc3[0][tl], 0, 0, 0);
                    acc3[1][tl] = __builtin_amdgcn_mfma_f32_16x16x16f16(w3b, a3u[tl], acc3[1][tl], 0, 0, 0);
                }
            }
#pragma unroll
            for (int v = 0; v < 2; ++v)
#pragma unroll
                for (int tl = 0; tl < 2; ++tl) {
                    int edge = 16*(2*th + tl) + ml;
                    bool ok = edge < NPART-1;
#pragma unroll
                    for (int i = 0; i < 4; ++i)
                        s[v][i] += ok ? fmaxf(acc3[v][tl][i], 0.f) : 0.f;
                }
        }
        // butterfly over edge lanes -> sEpp[r]
#pragma unroll
        for (int v = 0; v < 2; ++v) {
#pragma unroll
            for (int i = 0; i < 4; ++i) {
                s[v][i] += __shfl_xor(s[v][i], 1);
                s[v][i] += __shfl_xor(s[v][i], 2);
                s[v][i] += __shfl_xor(s[v][i], 4);
                s[v][i] += __shfl_xor(s[v][i], 8);
            }
            int col4 = v*16 + 4*q;
            if (ml == 0 && col4 < DE) {
                f32x4 o = {s[v][0], s[v][1], s[v][2], s[v][3]};
                *(half4v*)(sEpp + r*DE + col4) = pkcvt4(o);
            }
        }
    }

    // ================= P1b: pv groups, gv = wv (waves 0-4), t-pair halves ===
    if (wv < NVTX) {
        int gv = wv;
#pragma unroll
        for (int th = 0; th < 2; ++th) {
            half8 bA[2][2];
#pragma unroll
            for (int tl = 0; tl < 2; ++tl) {
                int p = 16*(2*th + tl) + ml;
                int sr = (p < NPART) ? p : 0;
#pragma unroll
                for (int kk = 0; kk < 2; ++kk) {
                    half8 u8 = *(const half8*)(sPvV + gv*64 + kk*32 + q*8);
                    half8 v8 = *(const half8*)(sPvA + sr*SR + kk*32 + q*8);
                    half8 s8 = u8 + v8;
#pragma unroll
                    for (int j = 0; j < 8; ++j) {
                        _Float16 vj = s8[j];
                        s8[j] = (vj > (_Float16)0.f) ? vj : (_Float16)0.f;
                    }
                    bA[tl][kk] = s8;
                }
            }
            f32x4 acc3[2][2];
#pragma unroll
            for (int v = 0; v < 2; ++v) {
                f32x4 bi = bias4(pv_b3, v*16 + 4*q, DE - 3);
#pragma unroll
                for (int tl = 0; tl < 2; ++tl) acc3[v][tl] = bi;
            }
#pragma unroll
            for (int u = 0; u < 4; ++u) {
                half8 w0 = pvw2p[(u*2 + 0)*64 + lane];
                half8 w1 = pvw2p[(u*2 + 1)*64 + lane];
                f32x4 bi2 = bias4(pv_b2, u*16 + 4*q, HID - 3);
                half4v a3u[2];
#pragma unroll
                for (int tl = 0; tl < 2; ++tl) {
                    f32x4 a = bi2;
                    a = __builtin_amdgcn_mfma_f32_16x16x32_f16(w0, bA[tl][0], a, 0, 0, 0);
                    a = __builtin_amdgcn_mfma_f32_16x16x32_f16(w1, bA[tl][1], a, 0, 0, 0);
                    a3u[tl] = relu4(pkcvt4(a));
                }
                half4v w3a = pvw3p16[(0*4 + u)*64 + lane];
                half4v w3b = pvw3p16[(1*4 + u)*64 + lane];
#pragma unroll
                for (int tl = 0; tl < 2; ++tl) {
                    acc3[0][tl] = __builtin_amdgcn_mfma_f32_16x16x16f16(w3a, a3u[tl], acc3[0][tl], 0, 0, 0);
                    acc3[1][tl] = __builtin_amdgcn_mfma_f32_16x16x16f16(w3b, a3u[tl], acc3[1][tl], 0, 0, 0);
                }
            }
#pragma unroll
            for (int v = 0; v < 2; ++v) {
                int col4 = v*16 + 4*q;
#pragma unroll
                for (int tl = 0; tl < 2; ++tl) {
                    int p = 16*(2*th + tl) + ml;
                    if (p < NPART && col4 < DE) {
                        half4v hv = relu4(pkcvt4(acc3[v][tl]));
                        *(half4v*)(sEpvP + (gv*NPART + p)*DE + col4) = hv;
                    }
                }
            }
        }
    }
    __syncthreads();

    // ================= P2: cin gather into sCin (aliases sFrA) ==============
    for (int idx = threadIdx.x; idx < NPART*64; idx += 512) {
        int p = idx >> 6;
        int k = idx & 63;
        _Float16 v;
        if (k < PFEAT) {
            v = (_Float16)x[((size_t)bb*PFEAT + k)*NPART + p];
        } else if (k < PFEAT + DE) {
            v = sEpp[p*DE + (k - PFEAT)];
        } else if (k < PFEAT + 2*DE) {
            int c = k - PFEAT - DE;
            float s = 0.f;
#pragma unroll
            for (int g5 = 0; g5 < NVTX; ++g5)
                s += (float)sEpvP[(g5*NPART + p)*DE + c];
            v = (_Float16)s;
        } else {
            v = (_Float16)0.f;
        }
        sCin[p*SR + k] = v;
    }
    __syncthreads();

    // ================= P3: object MLP (waves 0-3, tile = wv) ================
    if (wv < 4) {
        int p = 16*wv + ml;
        int sp = (p < NPART) ? p : 0;
        half8 bC[2];
#pragma unroll
        for (int kk = 0; kk < 2; ++kk)
            bC[kk] = *(const half8*)(sCin + sp*SR + kk*32 + q*8);

        f32x4 acc1[4];
#pragma unroll
        for (int u = 0; u < 4; ++u) {
            acc1[u] = bias4(fo_b1, u*16 + 4*q, HID - 3);
            acc1[u] = __builtin_amdgcn_mfma_f32_16x16x32_f16(fow1p[(u*2 + 0)*64 + lane], bC[0], acc1[u], 0, 0, 0);
            acc1[u] = __builtin_amdgcn_mfma_f32_16x16x32_f16(fow1p[(u*2 + 1)*64 + lane], bC[1], acc1[u], 0, 0, 0);
        }
        half4v a2[4];
#pragma unroll
        for (int u = 0; u < 4; ++u) a2[u] = relu4(pkcvt4(acc1[u]));

        f32x4 acc2[4];
#pragma unroll
        for (int u = 0; u < 4; ++u) {
            acc2[u] = bias4(fo_b2, u*16 + 4*q, HID - 3);
#pragma unroll
            for (int kt = 0; kt < 4; ++kt)
                acc2[u] = __builtin_amdgcn_mfma_f32_16x16x16f16(fow2p16[(u*4 + kt)*64 + lane], a2[kt], acc2[u], 0, 0, 0);
        }
        half4v a3[4];
#pragma unroll
        for (int u = 0; u < 4; ++u) a3[u] = relu4(pkcvt4(acc2[u]));

        f32x4 acc3[2];
#pragma unroll
        for (int v = 0; v < 2; ++v) {
            acc3[v] = bias4(fo_b3, v*16 + 4*q, DO - 3);
#pragma unroll
            for (int u = 0; u < 4; ++u)
                acc3[v] = __builtin_amdgcn_mfma_f32_16x16x16f16(fow3p16[(v*4 + u)*64 + lane], a3[u], acc3[v], 0, 0, 0);
        }
#pragma unroll
        for (int v = 0; v < 2; ++v) {
            float s[4];
            bool ok = p < NPART;
#pragma unroll
            for (int i = 0; i < 4; ++i)
                s[i] = ok ? fmaxf(acc3[v][i], 0.f) : 0.f;
#pragma unroll
            for (int i = 0; i < 4; ++i) {
                s[i] += __shfl_xor(s[i], 1);
                s[i] += __shfl_xor(s[i], 2);
                s[i] += __shfl_xor(s[i], 4);
                s[i] += __shfl_xor(s[i], 8);
            }
            int col4 = v*16 + 4*q;
            if (ml == 0 && col4 < DO) {
                f32x4 o = {s[0], s[1], s[2], s[3]};
                *(f32x4*)(sDsum[wv] + col4) = o;
            }
        }
    }
    __syncthreads();

    // ================= fc head (wave 0) =====================================
    if (wv == 0) {
        float tot = 0.f;
        if (lane < DO) {
#pragma unroll
            for (int w4 = 0; w4 < 4; ++w4) tot += sDsum[w4][lane];
        }
        float p0 = (lane < DO) ? tot * fcw[lane*NCLS + 0] : 0.f;
        float p1 = (lane < DO) ? tot * fcw[lane*NCLS + 1] : 0.f;
#pragma unroll
        for (int d = 1; d <= 16; d <<= 1) {
            p0 += __shfl_xor(p0, d);
            p1 += __shfl_xor(p1, d);
        }
        if (lane == 0) {
            out[bb*NCLS + 0] = p0 + fcb[0];
            out[bb*NCLS + 1] = p1 + fcb[1];
        }
    }
}

// ---------------------------------------------------------------------------
extern "C" void kernel_launch(void* const* d_in, const int* in_sizes, int n_in,
                              void* d_out, int out_size, void* d_ws, size_t ws_size,
                              hipStream_t stream)
{
    const float* x     = (const float*)d_in[0];
    const float* y     = (const float*)d_in[1];
    const float* fr_w1 = (const float*)d_in[2];
    const float* fr_b1 = (const float*)d_in[3];
    const float* fr_w2 = (const float*)d_in[4];
    const float* fr_b2 = (const float*)d_in[5];
    const float* fr_w3 = (const float*)d_in[6];
    const float* fr_b3 = (const float*)d_in[7];
    const float* pv_w1 = (const float*)d_in[8];
    const float* pv_b1 = (const float*)d_in[9];
    const float* pv_w2 = (const float*)d_in[10];
    const float* pv_b2 = (const float*)d_in[11];
    const float* pv_w3 = (const float*)d_in[12];
    const float* pv_b3 = (const float*)d_in[13];
    const float* fo_w1 = (const float*)d_in[14];
    const float* fo_b1 = (const float*)d_in[15];
    const float* fo_w2 = (const float*)d_in[16];
    const float* fo_b2 = (const float*)d_in[17];
    const float* fo_w3 = (const float*)d_in[18];
    const float* fo_b3 = (const float*)d_in[19];
    const float* fc_w  = (const float*)d_in[20];
    const float* fc_b  = (const float*)d_in[21];
    float* out = (float*)d_out;

    char* wsb = (char*)d_ws;
    size_t off = 0;
    auto alloc = [&](size_t bytes) { char* p = wsb + off; off += (bytes + 255) & ~(size_t)255; return p; };

    _Float16* frW2p   = (_Float16*)alloc(4096*2);
    _Float16* frW3p16 = (_Float16*)alloc(2048*2);
    _Float16* pvW2p   = (_Float16*)alloc(4096*2);
    _Float16* pvW3p16 = (_Float16*)alloc(2048*2);
    _Float16* foW1p   = (_Float16*)alloc(4096*2);
    _Float16* foW2p16 = (_Float16*)alloc(4096*2);
    _Float16* foW3p16 = (_Float16*)alloc(2048*2);

    pack_kernel<<<16, 256, 0, stream>>>(
        fr_w2, fr_w3, pv_w2, pv_w3, fo_w1, fo_w2, fo_w3,
        frW2p, frW3p16, pvW2p, pvW3p16, foW1p, foW2p16, foW3p16);

    fused_kernel<<<BATCH, 512, 0, stream>>>(
        x, y, fr_w1, fr_b1, fr_b2, fr_b3,
        pv_w1, pv_b1, pv_b2, pv_b3,
        fo_b1, fo_b2, fo_b3, fc_w, fc_b,
        (const half8*)frW2p, (const half4v*)frW3p16,
        (const half8*)pvW2p, (const half4v*)pvW3p16,
        (const half8*)foW1p, (const half4v*)foW2p16, (const half4v*)foW3p16,
        out);
}